// Round 1
// baseline (415.679 us; speedup 1.0000x reference)
//
#include <hip/hip_runtime.h>
#include <hip/hip_bf16.h>

#define DIM 512
#define BATCH 512
#define CCLS 100000
#define BM 128
#define BN 128
#define NT 782   // ceil(100000/128)

typedef __attribute__((ext_vector_type(8))) short bf16x8;
typedef __attribute__((ext_vector_type(4))) float f32x4;

__device__ __forceinline__ unsigned short f2bf(float f) {
  union { float f; unsigned int u; } v; v.f = f;
  unsigned int u = v.u;
  return (unsigned short)((u + 0x7fffu + ((u >> 16) & 1u)) >> 16);
}

__device__ __forceinline__ void async_copy16(const unsigned short* g, unsigned short* l) {
  __builtin_amdgcn_global_load_lds((const __attribute__((address_space(1))) void*)g,
                                   (__attribute__((address_space(3))) void*)l, 16, 0, 0);
}

// One wave per row: read fp32 row, L2-normalize, write bf16 row.
__global__ __launch_bounds__(256) void rownorm_bf16(const float* __restrict__ in,
                                                    unsigned short* __restrict__ out,
                                                    int R) {
  int wave = threadIdx.x >> 6;
  int lane = threadIdx.x & 63;
  int row = blockIdx.x * 4 + wave;
  if (row >= R) return;
  const float4* src = (const float4*)(in + (size_t)row * DIM);
  float4 v0 = src[lane];
  float4 v1 = src[lane + 64];
  float ss = v0.x*v0.x + v0.y*v0.y + v0.z*v0.z + v0.w*v0.w
           + v1.x*v1.x + v1.y*v1.y + v1.z*v1.z + v1.w*v1.w;
  #pragma unroll
  for (int off = 32; off > 0; off >>= 1) ss += __shfl_xor(ss, off, 64);
  float r = 1.0f / fmaxf(sqrtf(ss), 1e-12f);
  ushort4 o0, o1;
  o0.x = f2bf(v0.x * r); o0.y = f2bf(v0.y * r); o0.z = f2bf(v0.z * r); o0.w = f2bf(v0.w * r);
  o1.x = f2bf(v1.x * r); o1.y = f2bf(v1.y * r); o1.z = f2bf(v1.z * r); o1.w = f2bf(v1.w * r);
  ushort4* dst = (ushort4*)(out + (size_t)row * DIM);
  dst[lane]      = o0;
  dst[lane + 64] = o1;
}

// 128x128 tile GEMM (K=512, BK=64) with fused CosFace epilogue.
// A = x_n [512][512] bf16 row-major, B^T = wt_n [C][512] bf16 row-major.
// Epilogue: logit = 64*cos (- 64*0.35 at gt); partial[nt][m] = sum_n exp(logit-64);
// tgt[m] = margined target logit.
__global__ __launch_bounds__(256) void cosface_gemm(
    const unsigned short* __restrict__ xn,
    const unsigned short* __restrict__ wn,
    const int* __restrict__ gt,
    float* __restrict__ partial,
    float* __restrict__ tgt) {
  // LDS tiles: [row][8 chunks of 16B], XOR-swizzled chunk slots.
  __shared__ unsigned short lds_a[BM * 64];
  __shared__ unsigned short lds_b[BN * 64];
  __shared__ float lds_rowsum[BM];
  __shared__ int lds_gt[BM];

  const int tid = threadIdx.x;
  const int lane = tid & 63;
  const int w = tid >> 6;          // wave 0..3
  const int wm = w >> 1;           // wave row half
  const int wn_ = w & 1;           // wave col half
  const int mt = blockIdx.x;       // 0..3
  const int nt = blockIdx.y;       // 0..781

  // Staging source pointers: chunk c = j*256 + w*64 + lane; m=c>>3, qs=c&7,
  // global k-chunk qg = qs ^ (m&7) (XOR swizzle, stays within the row's 128B).
  const unsigned short* ga[4];
  const unsigned short* gb[4];
  #pragma unroll
  for (int j = 0; j < 4; ++j) {
    int c = j * 256 + w * 64 + lane;
    int m = c >> 3;
    int qg = (c & 7) ^ (m & 7);
    int rowA = mt * BM + m;
    int rowB = nt * BN + m;
    if (rowB >= CCLS) rowB = CCLS - 1;   // clamp; excluded in epilogue
    ga[j] = xn + (size_t)rowA * DIM + qg * 8;
    gb[j] = wn + (size_t)rowB * DIM + qg * 8;
  }

  f32x4 acc[4][4];
  #pragma unroll
  for (int i = 0; i < 4; ++i)
    #pragma unroll
    for (int j = 0; j < 4; ++j)
      acc[i][j] = (f32x4){0.f, 0.f, 0.f, 0.f};

  const int quad = lane >> 4;
  const int l15 = lane & 15;

  for (int kk = 0; kk < 8; ++kk) {
    #pragma unroll
    for (int j = 0; j < 4; ++j) {
      async_copy16(ga[j] + kk * 64, &lds_a[(j * 256 + w * 64) * 8]);
      async_copy16(gb[j] + kk * 64, &lds_b[(j * 256 + w * 64) * 8]);
    }
    __syncthreads();
    #pragma unroll
    for (int s = 0; s < 2; ++s) {
      bf16x8 af[4], bf[4];
      int q = s * 4 + quad;
      #pragma unroll
      for (int i = 0; i < 4; ++i) {
        int ml = wm * 64 + i * 16 + l15;
        af[i] = *(const bf16x8*)&lds_a[ml * 64 + ((q ^ (ml & 7)) * 8)];
        int nl = wn_ * 64 + i * 16 + l15;
        bf[i] = *(const bf16x8*)&lds_b[nl * 64 + ((q ^ (nl & 7)) * 8)];
      }
      #pragma unroll
      for (int i = 0; i < 4; ++i)
        #pragma unroll
        for (int j = 0; j < 4; ++j)
          acc[i][j] = __builtin_amdgcn_mfma_f32_16x16x32_bf16(af[i], bf[j], acc[i][j], 0, 0, 0);
    }
    __syncthreads();
  }

  // Epilogue
  if (tid < BM) {
    lds_rowsum[tid] = 0.f;
    lds_gt[tid] = gt[mt * BM + tid];
  }
  __syncthreads();

  #pragma unroll
  for (int i = 0; i < 4; ++i) {
    #pragma unroll
    for (int reg = 0; reg < 4; ++reg) {
      int m_loc = wm * 64 + i * 16 + quad * 4 + reg;
      int m_g = mt * BM + m_loc;
      int gtm = lds_gt[m_loc];
      float s = 0.f;
      #pragma unroll
      for (int j = 0; j < 4; ++j) {
        int n_g = nt * BN + wn_ * 64 + j * 16 + l15;
        float logit = 64.f * acc[i][j][reg];
        if (n_g == gtm) {
          logit -= 64.f * 0.35f;
          tgt[m_g] = logit;
        }
        if (n_g < CCLS) s += __expf(logit - 64.f);
      }
      #pragma unroll
      for (int off = 1; off < 16; off <<= 1) s += __shfl_xor(s, off, 64);
      if (l15 == 0) atomicAdd(&lds_rowsum[m_loc], s);
    }
  }
  __syncthreads();
  if (tid < BM) partial[(size_t)nt * BATCH + mt * BM + tid] = lds_rowsum[tid];
}

__global__ __launch_bounds__(512) void finalize(const float* __restrict__ partial,
                                                const float* __restrict__ tgt,
                                                float* __restrict__ out) {
  __shared__ float red[BATCH];
  int m = threadIdx.x;
  float s = 0.f;
  for (int t = 0; t < NT; ++t) s += partial[(size_t)t * BATCH + m];
  float nll = (logf(s) + 64.f) - tgt[m];
  red[m] = nll;
  __syncthreads();
  for (int k = 256; k > 0; k >>= 1) {
    if (m < k) red[m] += red[m + k];
    __syncthreads();
  }
  if (m == 0) out[0] = red[0] * (1.0f / BATCH);
}

extern "C" void kernel_launch(void* const* d_in, const int* in_sizes, int n_in,
                              void* d_out, int out_size, void* d_ws, size_t ws_size,
                              hipStream_t stream) {
  const float* x  = (const float*)d_in[0];
  const int*   gt = (const int*)d_in[1];
  const float* wt = (const float*)d_in[2];
  float* out = (float*)d_out;

  char* ws = (char*)d_ws;
  unsigned short* wn = (unsigned short*)ws;                                   // 102,400,000 B
  unsigned short* xn = (unsigned short*)(ws + 102400000);                     //     524,288 B
  float* partial     = (float*)(ws + 102400000 + 524288);                     //   1,601,536 B
  float* tgt         = (float*)(ws + 102400000 + 524288 + 1601536);           //       2,048 B

  rownorm_bf16<<<CCLS / 4, 256, 0, stream>>>(wt, wn, CCLS);
  rownorm_bf16<<<BATCH / 4, 256, 0, stream>>>(x, xn, BATCH);
  cosface_gemm<<<dim3(4, NT), 256, 0, stream>>>(xn, wn, gt, partial, tgt);
  finalize<<<1, BATCH, 0, stream>>>(partial, tgt, out);
}

// Round 2
// 365.800 us; speedup vs baseline: 1.1364x; 1.1364x over previous
//
#include <hip/hip_runtime.h>
#include <hip/hip_bf16.h>

#define DIM 512
#define BATCH 512
#define CCLS 100000
#define BM 128
#define BN 128
#define NT 782   // ceil(100000/128)

typedef __attribute__((ext_vector_type(8))) short bf16x8;
typedef __attribute__((ext_vector_type(4))) float f32x4;

__device__ __forceinline__ unsigned short f2bf(float f) {
  union { float f; unsigned int u; } v; v.f = f;
  unsigned int u = v.u;
  return (unsigned short)((u + 0x7fffu + ((u >> 16) & 1u)) >> 16);
}

__device__ __forceinline__ void async_copy16(const unsigned short* g, unsigned short* l) {
  __builtin_amdgcn_global_load_lds((const __attribute__((address_space(1))) void*)g,
                                   (__attribute__((address_space(3))) void*)l, 16, 0, 0);
}

// One wave per row: read fp32 row, L2-normalize, write bf16 row.
// Blocks [0, 25000) -> wt rows; blocks [25000, 25128) -> x rows.
__global__ __launch_bounds__(256) void rownorm_all(const float* __restrict__ wt,
                                                   const float* __restrict__ x,
                                                   unsigned short* __restrict__ wn,
                                                   unsigned short* __restrict__ xn) {
  int wave = threadIdx.x >> 6;
  int lane = threadIdx.x & 63;
  int row4 = blockIdx.x * 4 + wave;
  const float* in;
  unsigned short* out;
  int row;
  if (row4 < CCLS) { in = wt; out = wn; row = row4; }
  else             { in = x;  out = xn; row = row4 - CCLS; }
  const float4* src = (const float4*)(in + (size_t)row * DIM);
  float4 v0 = src[lane];
  float4 v1 = src[lane + 64];
  float ss = v0.x*v0.x + v0.y*v0.y + v0.z*v0.z + v0.w*v0.w
           + v1.x*v1.x + v1.y*v1.y + v1.z*v1.z + v1.w*v1.w;
  #pragma unroll
  for (int off = 32; off > 0; off >>= 1) ss += __shfl_xor(ss, off, 64);
  float r = 1.0f / fmaxf(sqrtf(ss), 1e-12f);
  ushort4 o0, o1;
  o0.x = f2bf(v0.x * r); o0.y = f2bf(v0.y * r); o0.z = f2bf(v0.z * r); o0.w = f2bf(v0.w * r);
  o1.x = f2bf(v1.x * r); o1.y = f2bf(v1.y * r); o1.z = f2bf(v1.z * r); o1.w = f2bf(v1.w * r);
  ushort4* dst = (ushort4*)(out + (size_t)row * DIM);
  dst[lane]      = o0;
  dst[lane + 64] = o1;
}

// 128x128 tile GEMM (K=512, BK=64) with fused CosFace epilogue.
// partial is TRANSPOSED: partial[m][nt] for coalesced finalize reads.
__global__ __launch_bounds__(256, 4) void cosface_gemm(
    const unsigned short* __restrict__ xn,
    const unsigned short* __restrict__ wn,
    const int* __restrict__ gt,
    float* __restrict__ partial,
    float* __restrict__ tgt) {
  __shared__ unsigned short lds_a[BM * 64];
  __shared__ unsigned short lds_b[BN * 64];
  __shared__ float lds_rowsum[BM];
  __shared__ int lds_gt[BM];

  const int tid = threadIdx.x;
  const int lane = tid & 63;
  const int w = tid >> 6;          // wave 0..3
  const int wm = w >> 1;           // wave row half
  const int wn_ = w & 1;           // wave col half
  const int mt = blockIdx.x;       // 0..3
  const int nt = blockIdx.y;       // 0..781

  // Epilogue LDS init (ordered before use by the K-loop's final barrier).
  if (tid < BM) {
    lds_rowsum[tid] = 0.f;
    lds_gt[tid] = gt[mt * BM + tid];
  }

  // Staging source pointers: chunk c = j*256 + w*64 + lane; m=c>>3, qs=c&7,
  // global k-chunk qg = qs ^ (m&7) (XOR swizzle, stays within the row's 128B).
  const unsigned short* ga[4];
  const unsigned short* gb[4];
  #pragma unroll
  for (int j = 0; j < 4; ++j) {
    int c = j * 256 + w * 64 + lane;
    int m = c >> 3;
    int qg = (c & 7) ^ (m & 7);
    int rowA = mt * BM + m;
    int rowB = nt * BN + m;
    if (rowB >= CCLS) rowB = CCLS - 1;   // clamp; excluded in epilogue
    ga[j] = xn + (size_t)rowA * DIM + qg * 8;
    gb[j] = wn + (size_t)rowB * DIM + qg * 8;
  }

  f32x4 acc[4][4];
  #pragma unroll
  for (int i = 0; i < 4; ++i)
    #pragma unroll
    for (int j = 0; j < 4; ++j)
      acc[i][j] = (f32x4){0.f, 0.f, 0.f, 0.f};

  const int quad = lane >> 4;
  const int l15 = lane & 15;

  for (int kk = 0; kk < 8; ++kk) {
    #pragma unroll
    for (int j = 0; j < 4; ++j) {
      async_copy16(ga[j] + kk * 64, &lds_a[(j * 256 + w * 64) * 8]);
      async_copy16(gb[j] + kk * 64, &lds_b[(j * 256 + w * 64) * 8]);
    }
    __syncthreads();
    #pragma unroll
    for (int s = 0; s < 2; ++s) {
      bf16x8 af[4], bf[4];
      int q = s * 4 + quad;
      #pragma unroll
      for (int i = 0; i < 4; ++i) {
        int ml = wm * 64 + i * 16 + l15;
        af[i] = *(const bf16x8*)&lds_a[ml * 64 + ((q ^ (ml & 7)) * 8)];
        int nl = wn_ * 64 + i * 16 + l15;
        bf[i] = *(const bf16x8*)&lds_b[nl * 64 + ((q ^ (nl & 7)) * 8)];
      }
      #pragma unroll
      for (int i = 0; i < 4; ++i)
        #pragma unroll
        for (int j = 0; j < 4; ++j)
          acc[i][j] = __builtin_amdgcn_mfma_f32_16x16x32_bf16(af[i], bf[j], acc[i][j], 0, 0, 0);
    }
    __syncthreads();
  }

  // Epilogue
  #pragma unroll
  for (int i = 0; i < 4; ++i) {
    #pragma unroll
    for (int reg = 0; reg < 4; ++reg) {
      int m_loc = wm * 64 + i * 16 + quad * 4 + reg;
      int m_g = mt * BM + m_loc;
      int gtm = lds_gt[m_loc];
      float s = 0.f;
      #pragma unroll
      for (int j = 0; j < 4; ++j) {
        int n_g = nt * BN + wn_ * 64 + j * 16 + l15;
        float logit = 64.f * acc[i][j][reg];
        if (n_g == gtm) {
          logit -= 64.f * 0.35f;
          tgt[m_g] = logit;
        }
        if (n_g < CCLS) s += __expf(logit - 64.f);
      }
      #pragma unroll
      for (int off = 1; off < 16; off <<= 1) s += __shfl_xor(s, off, 64);
      if (l15 == 0) atomicAdd(&lds_rowsum[m_loc], s);
    }
  }
  __syncthreads();
  if (tid < BM)
    partial[(size_t)(mt * BM + tid) * NT + nt] = lds_rowsum[tid];
}

// Stage 1: one wave per row m — sum partial[m][0..NT) (contiguous), emit nll[m].
__global__ __launch_bounds__(64) void nll_rows(const float* __restrict__ partial,
                                               const float* __restrict__ tgt,
                                               float* __restrict__ nll) {
  int m = blockIdx.x;
  int lane = threadIdx.x;
  const float* row = partial + (size_t)m * NT;
  float s = 0.f;
  for (int t = lane; t < NT; t += 64) s += row[t];
  #pragma unroll
  for (int off = 32; off > 0; off >>= 1) s += __shfl_xor(s, off, 64);
  if (lane == 0) nll[m] = (logf(s) + 64.f) - tgt[m];
}

// Stage 2: mean over 512 rows.
__global__ __launch_bounds__(512) void reduce_mean(const float* __restrict__ nll,
                                                   float* __restrict__ out) {
  __shared__ float red[BATCH];
  int m = threadIdx.x;
  red[m] = nll[m];
  __syncthreads();
  for (int k = 256; k > 0; k >>= 1) {
    if (m < k) red[m] += red[m + k];
    __syncthreads();
  }
  if (m == 0) out[0] = red[0] * (1.0f / BATCH);
}

extern "C" void kernel_launch(void* const* d_in, const int* in_sizes, int n_in,
                              void* d_out, int out_size, void* d_ws, size_t ws_size,
                              hipStream_t stream) {
  const float* x  = (const float*)d_in[0];
  const int*   gt = (const int*)d_in[1];
  const float* wt = (const float*)d_in[2];
  float* out = (float*)d_out;

  char* ws = (char*)d_ws;
  unsigned short* wn = (unsigned short*)ws;                                   // 102,400,000 B
  unsigned short* xn = (unsigned short*)(ws + 102400000);                     //     524,288 B
  float* partial     = (float*)(ws + 102400000 + 524288);                     //   1,601,536 B
  float* tgt         = (float*)(ws + 102400000 + 524288 + 1601536);           //       2,048 B
  float* nll         = (float*)(ws + 102400000 + 524288 + 1601536 + 2048);    //       2,048 B

  rownorm_all<<<(CCLS + BATCH) / 4, 256, 0, stream>>>(wt, x, wn, xn);
  cosface_gemm<<<dim3(4, NT), 256, 0, stream>>>(xn, wn, gt, partial, tgt);
  nll_rows<<<BATCH, 64, 0, stream>>>(partial, tgt, nll);
  reduce_mean<<<1, BATCH, 0, stream>>>(nll, out);
}